// Round 12
// baseline (120.971 us; speedup 1.0000x reference)
//
#include <hip/hip_runtime.h>
#include <hip/hip_bf16.h>
#include <stdint.h>

// B=8, T=1024, D=U=640, H=10, d=64
#define B_DIM 8
#define T_DIM 1024
#define D_DIM 640
#define H_DIM 10
#define LOG2E 1.442695041f

typedef unsigned short ushort_t;
typedef __attribute__((ext_vector_type(8))) short short8;
typedef __attribute__((ext_vector_type(4))) float f32x4;
typedef __attribute__((ext_vector_type(16))) float f32x16;
typedef __attribute__((ext_vector_type(4))) unsigned int u32x4;

__device__ __forceinline__ ushort_t f32_to_bf16(float f) {
    unsigned int u = __builtin_bit_cast(unsigned int, f);
    u += 0x7fffu + ((u >> 16) & 1u);   // RNE
    return (ushort_t)(u >> 16);
}
__device__ __forceinline__ float v_exp2(float x) {
    float r; asm("v_exp_f32 %0, %1" : "=v"(r) : "v"(x)); return r;
}
__device__ __forceinline__ unsigned cvt_pk_bf16(float a, float b) {
    unsigned r; asm("v_cvt_pk_bf16_f32 %0, %1, %2" : "=v"(r) : "v"(a), "v"(b)); return r;
}

// strips sorted heavy-first by tile count: 0(16),31(16),30(16),29(15),...
__constant__ int SPERM[32] = {0,31,30,29,28,27,26,25,24,23,22,21,20,19,18,17,
                              16,15,14,13,12,11,10,9,8,7,6,5,4,3,2,1};

// ---------------------------------------------------------------------------
// Fragment layouts (16x16x32 MFMA operands):
//  XF (A-op): XF[(m16*20 + kc)*512 + lane*8 + jj] = x[m16*16 + (lane&15)]
//                                                    [kc*32 + (lane>>4)*8 + jj]
//  WF (B-op): WF[((w*40 + n16)*20 + kc)*512 + lane*8 + jj]
//              = W_w[kc*32 + (lane>>4)*8 + jj][n16*16 + (lane&15)]
// ---------------------------------------------------------------------------

// ---------------------------------------------------------------------------
// Kernel A: fused { W -> WF fragments (blocks 0..299),
//                   x -> XF fragments (blocks 300..811) }
// ---------------------------------------------------------------------------
__global__ __launch_bounds__(256) void convwt(
    const float* __restrict__ x,
    const float* __restrict__ Wq, const float* __restrict__ Wk, const float* __restrict__ Wv,
    ushort_t* __restrict__ XF, ushort_t* __restrict__ WF)
{
    const int tid = threadIdx.x;
    if (blockIdx.x < 300) {
        const int w = blockIdx.x / 100, rem = blockIdx.x % 100;
        const int k0 = (rem % 10) * 64, n0 = (rem / 10) * 64;
        const float* W = (w == 0) ? Wq : (w == 1) ? Wk : Wv;

        __shared__ alignas(16) ushort_t st[64][72];   // [k][n]
        const int r = tid >> 2, cs = (tid & 3) * 16;
        #pragma unroll
        for (int j = 0; j < 4; ++j) {
            float4 v = *reinterpret_cast<const float4*>(
                &W[(size_t)(k0 + r) * D_DIM + n0 + cs + j * 4]);
            st[r][cs + j * 4 + 0] = f32_to_bf16(v.x);
            st[r][cs + j * 4 + 1] = f32_to_bf16(v.y);
            st[r][cs + j * 4 + 2] = f32_to_bf16(v.z);
            st[r][cs + j * 4 + 3] = f32_to_bf16(v.w);
        }
        __syncthreads();
        // emit 8 fragments (4 n16 x 2 kc); 2 chunks of 16B per thread
        #pragma unroll
        for (int q = 0; q < 2; ++q) {
            int c = tid * 2 + q;
            int fi = c >> 6, lane = c & 63;
            int n16l = fi >> 1, kcl = fi & 1;
            int nl = n16l * 16 + (lane & 15);
            int klb = kcl * 32 + (lane >> 4) * 8;
            ushort_t tmp[8];
            #pragma unroll
            for (int jj = 0; jj < 8; ++jj) tmp[jj] = st[klb + jj][nl];
            size_t frag = ((size_t)w * 40 + (n0 >> 4) + n16l) * 20 + (k0 >> 5) + kcl;
            *reinterpret_cast<short8*>(&WF[frag * 512 + lane * 8]) =
                *reinterpret_cast<const short8*>(tmp);
        }
    } else {
        const int mb = blockIdx.x - 300;   // m16 index 0..511
        __shared__ alignas(16) ushort_t xt[16][132];
        const int fl = tid * 2;
        const int row = fl >> 5, c4 = fl & 31;        // 32 float4 per row
        const int lane = tid & 63, wv = tid >> 6;
        const int lo = lane & 15, g = lane >> 4;
        #pragma unroll
        for (int sl = 0; sl < 5; ++sl) {
            const float* src = &x[((size_t)mb * 16 + row) * D_DIM + sl * 128 + c4 * 4];
            float4 v0 = *reinterpret_cast<const float4*>(src);
            float4 v1 = *reinterpret_cast<const float4*>(src + 4);
            ushort_t o[8] = {f32_to_bf16(v0.x), f32_to_bf16(v0.y), f32_to_bf16(v0.z),
                             f32_to_bf16(v0.w), f32_to_bf16(v1.x), f32_to_bf16(v1.y),
                             f32_to_bf16(v1.z), f32_to_bf16(v1.w)};
            *reinterpret_cast<short8*>(&xt[row][c4 * 4]) =
                *reinterpret_cast<const short8*>(o);
            __syncthreads();
            // wave wv emits fragment kc_local = wv of this 128-k slice
            short8 val = *reinterpret_cast<const short8*>(&xt[lo][wv * 32 + g * 8]);
            *reinterpret_cast<short8*>(
                &XF[(((size_t)mb * 20) + sl * 4 + wv) * 512 + lane * 8]) = val;
            __syncthreads();
        }
    }
}

// ---------------------------------------------------------------------------
// Kernel B: barrier-free, LDS-free bf16 MFMA GEMM. One WAVE = one 64x64
// output tile; all operand loads are coalesced dwordx4 from fragment buffers.
// Same-batch m-tiles pin to one XCD (b == xcd), matching attn's consumption.
// Outputs in 32x32x16 fragment layouts (QF/KF/VF) + ballot sign masks.
// ---------------------------------------------------------------------------
__global__ __launch_bounds__(256, 4) void gemm_qkv(
    const ushort_t* __restrict__ XF, const ushort_t* __restrict__ WF,
    const int* __restrict__ msk,
    ushort_t* __restrict__ QF, ushort_t* __restrict__ KF, ushort_t* __restrict__ VF,
    float* __restrict__ qs, ushort_t* __restrict__ km16)
{
    const int tid = threadIdx.x, lane = tid & 63, wave = tid >> 6;
    const int lo = lane & 15, g = lane >> 4;
    const int bid = blockIdx.x;
    const int xcd = bid & 7;
    const int gid = (bid >> 3) * 4 + wave;   // 0..479 within xcd
    const int w = gid / 160;                  // 0..2  (Q,K,V)
    const int rem = gid - w * 160;
    const int nt = rem >> 4;                  // 0..9   (head / 64-col tile)
    const int mt = xcd * 16 + (rem & 15);     // 0..127 (64-row tile)

    const ushort_t* XA = XF + (size_t)mt * 4 * 20 * 512;
    const ushort_t* WB = WF + ((size_t)w * 40 + nt * 4) * 20 * 512;

    f32x4 acc[4][4];
    #pragma unroll
    for (int i = 0; i < 4; ++i)
        #pragma unroll
        for (int jj = 0; jj < 4; ++jj) acc[i][jj] = (f32x4){0.f, 0.f, 0.f, 0.f};

#define LDA(DST, KC) do {                                                        \
        _Pragma("unroll")                                                        \
        for (int i_ = 0; i_ < 4; ++i_)                                           \
            DST[i_] = *reinterpret_cast<const short8*>(                          \
                &XA[((size_t)(i_ * 20) + (KC)) * 512 + lane * 8]);               \
    } while (0)
#define LDB(DST, KC) do {                                                        \
        _Pragma("unroll")                                                        \
        for (int j_ = 0; j_ < 4; ++j_)                                           \
            DST[j_] = *reinterpret_cast<const short8*>(                          \
                &WB[((size_t)(j_ * 20) + (KC)) * 512 + lane * 8]);               \
    } while (0)
#define MM(AF, BF) do {                                                          \
        __builtin_amdgcn_s_setprio(1);                                           \
        _Pragma("unroll")                                                        \
        for (int mi_ = 0; mi_ < 4; ++mi_)                                        \
            _Pragma("unroll")                                                    \
            for (int ni_ = 0; ni_ < 4; ++ni_)                                    \
                acc[mi_][ni_] = __builtin_amdgcn_mfma_f32_16x16x32_bf16(         \
                    AF[mi_], BF[ni_], acc[mi_][ni_], 0, 0, 0);                   \
        __builtin_amdgcn_s_setprio(0);                                           \
    } while (0)

    short8 a0[4], a1[4], b0[4];
    LDA(a0, 0);
    #pragma unroll
    for (int kc = 0; kc < 20; kc += 2) {
        LDA(a1, kc + 1);
        LDB(b0, kc);
        MM(a0, b0);
        if (kc + 2 < 20) LDA(a0, kc + 2);
        LDB(b0, kc + 1);
        MM(a1, b0);
    }
#undef LDA
#undef LDB
#undef MM

    const int M0 = mt * 64;                  // global row base
    const int N0 = nt * 64;
    const int hh = nt;                       // head
    const int bb = M0 >> 10;                 // batch (== xcd)
    const int hb = hh * 8 + bb;
    const int Mloc = M0 & 1023;
    const int ktw = Mloc >> 6;               // 64-row tile within batch

    if (w == 2) {
        // V -> VF fragment layout; 4 consecutive tokens pack into ushort4
        const int hiv = g >> 1, jj0 = (g & 1) * 4;
        #pragma unroll
        for (int mi = 0; mi < 4; ++mi)
            #pragma unroll
            for (int ni = 0; ni < 4; ++ni) {
                const int df = ni >> 1, l31v = (ni & 1) * 16 + lo;
                size_t idx = ((((size_t)(hb * 16 + ktw) * 4 + mi) * 2 + df) * 64
                              + hiv * 32 + l31v) * 8 + jj0;
                ushort4 o = make_ushort4(f32_to_bf16(acc[mi][ni][0]), f32_to_bf16(acc[mi][ni][1]),
                                         f32_to_bf16(acc[mi][ni][2]), f32_to_bf16(acc[mi][ni][3]));
                *reinterpret_cast<ushort4*>(&VF[idx]) = o;
            }
    } else {
        // sign masks via ballot: row-nonzero = OR over the 16 lanes of the row
        #pragma unroll
        for (int mi = 0; mi < 4; ++mi)
            #pragma unroll
            for (int r = 0; r < 4; ++r) {
                float s_ = fabsf(acc[mi][0][r]) + fabsf(acc[mi][1][r])
                         + fabsf(acc[mi][2][r]) + fabsf(acc[mi][3][r]);
                unsigned long long bal = __ballot(s_ != 0.f);
                if (lo == 0) {
                    int row = M0 + mi * 16 + g * 4 + r;
                    int rowid = hh * 8192 + row;
                    bool nz = ((bal >> (g * 16)) & 0xFFFFull) != 0ull;
                    if (w == 0) qs[rowid] = (nz ? 1.f : 0.f) * (float)msk[row];
                    else        km16[rowid] = nz ? (ushort_t)0x3F80 : (ushort_t)0;
                }
            }
        // fragment-layout stores
        const int hi2 = lo >> 3, jjq = lo & 7;
        const int s32base = Mloc >> 5;
        #pragma unroll
        for (int mi = 0; mi < 4; ++mi)
            #pragma unroll
            for (int ni = 0; ni < 4; ++ni)
                #pragma unroll
                for (int r = 0; r < 4; ++r) {
                    int l31 = (mi & 1) * 16 + g * 4 + r;
                    if (w == 0) {
                        int s32 = s32base + (mi >> 1);
                        size_t idx = (((size_t)(hb * 32 + s32) * 4 + ni) * 64
                                      + hi2 * 32 + l31) * 8 + jjq;
                        QF[idx] = f32_to_bf16(acc[mi][ni][r]);
                    } else {
                        int f = (mi >> 1) & 1;
                        size_t idx = ((((size_t)(hb * 16 + ktw) * 2 + f) * 4 + ni) * 64
                                      + hi2 * 32 + l31) * 8 + jjq;
                        KF[idx] = f32_to_bf16(acc[mi][ni][r]);
                    }
                }
    }
}

// ---------------------------------------------------------------------------
// Kernel C: flash attention with 4-way k-split per strip (unchanged).
// ---------------------------------------------------------------------------
#define DO_TILE(KT_IDX) do {                                                     \
    const int k0_ = (KT_IDX) * 64;                                               \
    const ushort_t* KT_ = &KFh[(size_t)(KT_IDX) * 4096];                         \
    const ushort_t* VT_ = &VFh[(size_t)(KT_IDX) * 4096];                         \
    short8 kA_[2][4];                                                            \
    _Pragma("unroll")                                                            \
    for (int f_ = 0; f_ < 2; ++f_)                                               \
        _Pragma("unroll")                                                        \
        for (int kc_ = 0; kc_ < 4; ++kc_)                                        \
            kA_[f_][kc_] = *reinterpret_cast<const short8*>(                     \
                &KT_[(f_ * 4 + kc_) * 512 + lane * 8]);                          \
    short8 vfA_[2][2], vfB_[2][2];                                               \
    _Pragma("unroll")                                                            \
    for (int c_ = 0; c_ < 2; ++c_)                                               \
        _Pragma("unroll")                                                        \
        for (int df_ = 0; df_ < 2; ++df_)                                        \
            vfA_[c_][df_] = *reinterpret_cast<const short8*>(                    \
                &VT_[(c_ * 2 + df_) * 512 + lane * 8]);                          \
    ushort4 kq_[2][4];                                                           \
    _Pragma("unroll")                                                            \
    for (int f_ = 0; f_ < 2; ++f_)                                               \
        _Pragma("unroll")                                                        \
        for (int rr_ = 0; rr_ < 4; ++rr_)                                        \
            kq_[f_][rr_] = *reinterpret_cast<const ushort4*>(                    \
                &kmr[k0_ + f_ * 32 + rr_ * 8 + hi * 4]);                         \
    unsigned pk_[2][8];                                                          \
    _Pragma("unroll")                                                            \
    for (int f_ = 0; f_ < 2; ++f_) {                                             \
        f32x16 sf_;                                                              \
        _Pragma("unroll")                                                        \
        for (int i_ = 0; i_ < 16; ++i_) sf_[i_] = 0.f;                           \
        __builtin_amdgcn_s_setprio(1);                                           \
        _Pragma("unroll")                                                        \
        for (int kc_ = 0; kc_ < 4; ++kc_)                                        \
            sf_ = __builtin_amdgcn_mfma_f32_32x32x16_bf16(kA_[f_][kc_],          \
                                                          qf[kc_], sf_, 0, 0, 0);\
        __builtin_amdgcn_s_setprio(0);                                           \
        if (f_ == 0) {                                                           \
            _Pragma("unroll")                                                    \
            for (int c_ = 0; c_ < 2; ++c_)                                       \
                _Pragma("unroll")                                                \
                for (int df_ = 0; df_ < 2; ++df_)                                \
                    vfB_[c_][df_] = *reinterpret_cast<const short8*>(            \
                        &VT_[((c_ + 2) * 2 + df_) * 512 + lane * 8]);            \
        }                                                                        \
        _Pragma("unroll")                                                        \
        for (int rr_ = 0; rr_ < 4; ++rr_) {                                      \
            const int kbase_ = k0_ + f_ * 32 + rr_ * 8 + hi * 4;                 \
            const ushort_t* kmv_ =                                               \
                reinterpret_cast<const ushort_t*>(&kq_[f_][rr_]);                \
            float p_[4];                                                         \
            _Pragma("unroll")                                                    \
            for (int ri_ = 0; ri_ < 4; ++ri_) {                                  \
                float cc_ = (kbase_ + ri_ >= trow) ? cB : cA;                    \
                cc_ = kmv_[ri_] ? cc_ : -1e30f;                                  \
                p_[ri_] = v_exp2(fmaf(sf_[rr_ * 4 + ri_], S2, cc_));             \
                lacc += p_[ri_];                                                 \
            }                                                                    \
            pk_[f_][rr_ * 2 + 0] = cvt_pk_bf16(p_[0], p_[1]);                    \
            pk_[f_][rr_ * 2 + 1] = cvt_pk_bf16(p_[2], p_[3]);                    \
        }                                                                        \
    }                                                                            \
    _Pragma("unroll")                                                            \
    for (int c_ = 0; c_ < 4; ++c_) {                                             \
        const int f_ = c_ >> 1, o_ = (c_ & 1) * 4;                               \
        unsigned a0_ = pk_[f_][o_ + 0], b0_ = pk_[f_][o_ + 2];                   \
        unsigned a1_ = pk_[f_][o_ + 1], b1_ = pk_[f_][o_ + 3];                   \
        if (v1) {                                                                \
            asm volatile("v_permlane32_swap_b32 %0, %1" : "+v"(b0_), "+v"(a0_)); \
            asm volatile("v_permlane32_swap_b32 %0, %1" : "+v"(b1_), "+v"(a1_)); \
        } else {                                                                 \
            asm volatile("v_permlane32_swap_b32 %0, %1" : "+v"(a0_), "+v"(b0_)); \
            asm volatile("v_permlane32_swap_b32 %0, %1" : "+v"(a1_), "+v"(b1_)); \
        }                                                                        \
        u32x4 pau_ = {a0_, a1_, b0_, b1_};                                       \
        short8 pa_ = __builtin_bit_cast(short8, pau_);                           \
        short8 v0_ = (c_ < 2) ? vfA_[c_][0] : vfB_[c_ - 2][0];                   \
        short8 v1f_ = (c_ < 2) ? vfA_[c_][1] : vfB_[c_ - 2][1];                  \
        __builtin_amdgcn_s_setprio(1);                                           \
        of0 = __builtin_amdgcn_mfma_f32_32x32x16_bf16(pa_, v0_, of0, 0, 0, 0);   \
        of1 = __builtin_amdgcn_mfma_f32_32x32x16_bf16(pa_, v1f_, of1, 0, 0, 0);  \
        __builtin_amdgcn_s_setprio(0);                                           \
    }                                                                            \
} while (0)

__global__ __launch_bounds__(256, 3) void attn_strip(
    const ushort_t* __restrict__ QF, const ushort_t* __restrict__ KF,
    const ushort_t* __restrict__ VF, const float* __restrict__ qs,
    const ushort_t* __restrict__ km16, float* __restrict__ out)
{
    __shared__ alignas(16) float mrg[3 * 64 * 36];   // 27,648 B

    const int tid = threadIdx.x, lane = tid & 63, wave = tid >> 6;
    const int l31 = lane & 31, hi = lane >> 5;

    // mapping: block = (b,h, strip). same-(b,h) on one XCD; heavy strips first.
    const int bid = blockIdx.x;                 // 0..2559
    const int xcd = bid & 7, i = bid >> 3;      // i 0..319
    const int sr = i / 10, grp = i % 10;
    const int g8 = xcd + 8 * grp;               // (b,h) group 0..79
    const int s = SPERM[sr], q0 = s * 32;
    const int b = g8 & 7, h = g8 >> 3, hb = h * 8 + b;

    // --- probe permlane32_swap direction (HW variant), wave-uniform ---
    unsigned pva = (unsigned)lane, pvb = 64u + (unsigned)lane;
    asm volatile("v_permlane32_swap_b32 %0, %1" : "+v"(pva), "+v"(pvb));
    const bool v1 = (__builtin_amdgcn_readfirstlane((int)pva) >= 96);

    const ushort_t* QFh = QF + (size_t)(hb * 32 + s) * 2048;
    const ushort_t* KFh = KF + (size_t)hb * 16 * 4096;
    const ushort_t* VFh = VF + (size_t)hb * 16 * 4096;
    const ushort_t* kmr = km16 + (size_t)hb * 1024;

    // Q fragments (B-operand), loop-invariant; all 4 waves load same -> L1 hit
    short8 qf[4];
    #pragma unroll
    for (int kc = 0; kc < 4; ++kc)
        qf[kc] = *reinterpret_cast<const short8*>(&QFh[kc * 512 + lane * 8]);

    // per-row shift M: any unpadded key strictly before row q0+l31?
    bool anyPrior = false;
    for (int c = 0; c < (q0 >> 6); ++c) {
        ushort_t v = kmr[c * 64 + lane];
        anyPrior = anyPrior || (__ballot(v != 0) != 0ull);
    }
    float M;
    {
        ushort_t v = kmr[(q0 & ~63) + lane];
        unsigned long long bal = __ballot(v != 0);
        unsigned long long pre = bal & ((1ull << ((q0 & 63) + l31)) - 1ull);
        M = (anyPrior || pre != 0ull) ? 16.f : -9984.f;
    }
    const float cA = -M * LOG2E;
    const float cB = cA - 10000.0f * LOG2E;
    const float S2 = 0.125f * LOG2E;
    const int trow = q0 + l31;

    float lacc = 0.f;
    f32x16 of0, of1;
    #pragma unroll
    for (int i2 = 0; i2 < 16; ++i2) { of0[i2] = 0.f; of1[i2] = 0.f; }

    const int ktend = (s == 0) ? 16 : ((s >> 1) + 1);

    // wave's interleaved tile subset
    for (int kt = wave; kt < ktend; kt += 4)
        DO_TILE(kt);

    // ---- merge partials: waves 1..3 -> LDS, wave 0 sums ----
    if (wave != 0) {
        float* dst = &mrg[((wave - 1) * 64 + lane) * 36];
        #pragma unroll
        for (int q = 0; q < 4; ++q) {
            reinterpret_cast<float4*>(dst)[q] =
                make_float4(of0[q * 4 + 0], of0[q * 4 + 1], of0[q * 4 + 2], of0[q * 4 + 3]);
            reinterpret_cast<float4*>(dst)[4 + q] =
                make_float4(of1[q * 4 + 0], of1[q * 4 + 1], of1[q * 4 + 2], of1[q * 4 + 3]);
        }
        dst[32] = lacc;
    }
    __syncthreads();
    if (wave == 0) {
        #pragma unroll
        for (int w2 = 0; w2 < 3; ++w2) {
            const float* src = &mrg[(w2 * 64 + lane) * 36];
            #pragma unroll
            for (int q = 0; q < 4; ++q) {
                float4 t0 = reinterpret_cast<const float4*>(src)[q];
                of0[q * 4 + 0] += t0.x; of0[q * 4 + 1] += t0.y;
                of0[q * 4 + 2] += t0.z; of0[q * 4 + 3] += t0.w;
                float4 t1 = reinterpret_cast<const float4*>(src)[4 + q];
                of1[q * 4 + 0] += t1.x; of1[q * 4 + 1] += t1.y;
                of1[q * 4 + 2] += t1.z; of1[q * 4 + 3] += t1.w;
            }
            lacc += src[32];
        }
        float ltot = lacc + __shfl_xor(lacc, 32);
        float scale = qs[(size_t)hb * 1024 + q0 + l31] / ltot;   // lane l: row l31
        const size_t obase = ((size_t)b * T_DIM + q0) * D_DIM + h * 64;
        #pragma unroll
        for (int reg = 0; reg < 16; ++reg) {
            const int qrow = (reg & 3) + 8 * (reg >> 2) + 4 * hi;
            const float sc = __shfl(scale, qrow);
            out[obase + (size_t)qrow * D_DIM + l31]      = of0[reg] * sc;
            out[obase + (size_t)qrow * D_DIM + 32 + l31] = of1[reg] * sc;
        }
    }
}

// ---------------------------------------------------------------------------
extern "C" void kernel_launch(void* const* d_in, const int* in_sizes, int n_in,
                              void* d_out, int out_size, void* d_ws, size_t ws_size,
                              hipStream_t stream)
{
    const float* x   = (const float*)d_in[0];
    const int*   msk = (const int*)d_in[1];
    const float* Wq  = (const float*)d_in[2];
    const float* Wk  = (const float*)d_in[3];
    const float* Wv  = (const float*)d_in[4];
    float* out = (float*)d_out;

    // workspace layout (bytes)
    char* ws = (char*)d_ws;
    ushort_t* XF = (ushort_t*)(ws);                    // 10,485,760
    ushort_t* WF = (ushort_t*)(ws + 10485760);         //  2,457,600
    ushort_t* QF = (ushort_t*)(ws + 12943360);         // 10,485,760
    ushort_t* KF = (ushort_t*)(ws + 23429120);         // 10,485,760
    ushort_t* VF = (ushort_t*)(ws + 33914880);         // 10,485,760
    float*    qs = (float*)(ws + 44400640);            //    327,680
    ushort_t* km = (ushort_t*)(ws + 44728320);         //    163,840
    if (ws_size < 44892160) return;

    convwt<<<812, 256, 0, stream>>>(x, Wq, Wk, Wv, XF, WF);
    gemm_qkv<<<960, 256, 0, stream>>>(XF, WF, msk, QF, KF, VF, qs, km);
    attn_strip<<<2560, 256, 0, stream>>>(QF, KF, VF, qs, km, out);
}